// Round 12
// baseline (136.516 us; speedup 1.0000x reference)
//
#include <hip/hip_runtime.h>
#include <math.h>

#define PI_F 3.14159274f        /* fp32 rounding of 3.141592653589 (== pi in fp32) */
#define STEP (5.5f/24.0f)       /* linspace(0.5, 6.0, 25) step */

constexpr int BATCH = 8;
constexpr int NATOM = 256;
constexpr int MNBR  = 100;
constexpr int NB    = 25;
constexpr int NATOT = BATCH * NATOM;   // 2048
constexpr int ABLK  = 4;               // atoms per main block
constexpr int NMBLK = NATOT / ABLK;    // 512 main blocks
constexpr int PPB   = NMBLK / BATCH;   // 64 force partials per batch

// ws layout (float offsets). W1 folded per center-type t (Imagetype in {1..4},
// plus padded type 0): W1t[t][jo][q] = sum_i W1[jo][k*25+i*5+j]*nemb[t][i],
// q = k*5+j (125-wide). H (125-wide) never leaves LDS in the fused kernel.
constexpr int OFF_W1T  = 0;            // [5][100][125]
constexpr int OFF_W1TT = 62500;        // [5][125][100] transposed
constexpr int OFF_W2T  = 125000;       // [100][100]
constexpr int OFF_W3T  = 135000;       // [100][100]
constexpr int OFF_PART = 145000;       // [512][768] force partials
constexpr size_t WS_NEED = (size_t)(OFF_PART + NMBLK * 768) * 4;   // ~2.15 MB

// ---------------------------------------------------------------------------
// K0: weight prep. Blocks 0..499: (t,jo) -> W1t / W1tT. Blocks 500..599:
//     transpose W2/W3. Tiny (~3 us).
// ---------------------------------------------------------------------------
__global__ __launch_bounds__(128)
void k_prep(const float* __restrict__ nemb, const float* __restrict__ W1,
            const float* __restrict__ W2, const float* __restrict__ W3,
            float* __restrict__ ws)
{
    int bid = blockIdx.x, tid = threadIdx.x;
    if (bid < 500) {
        int t = bid / 100, jo = bid - (bid / 100) * 100;
        if (tid < 125) {
            int k = tid / 5, j = tid - (tid / 5) * 5;
            float s = 0.f;
            #pragma unroll
            for (int i = 0; i < 5; i++)
                s = fmaf(W1[jo * 625 + k * 25 + i * 5 + j], nemb[t * 5 + i], s);
            ws[OFF_W1T  + (t * 100 + jo) * 125 + tid] = s;
            ws[OFF_W1TT + t * 12500 + tid * 100 + jo] = s;
        }
    } else {
        int jo = bid - 500;
        if (tid < 100) {
            ws[OFF_W2T + tid * 100 + jo] = W2[jo * 100 + tid];
            ws[OFF_W3T + tid * 100 + jo] = W3[jo * 100 + tid];
        }
    }
}

// ---------------------------------------------------------------------------
// K1: FUSED per-atom pipeline, 4 atoms/block (512 blocks x 512 thr, ~37 KB LDS,
//     2 blocks/CU). geometry -> H (feat recomputed via exp, never stored) ->
//     MLP fwd (coalesced W1tT/W2T/W3T) -> Ei -> MLP bwd -> dH (in LDS) ->
//     force + LDS scatter -> per-block partials. No H/dH global round-trip.
//     cond-guard folded: cut_s/sin_s zeroed when !(0<r<6) so feat & dfc == 0.
// ---------------------------------------------------------------------------
template<bool USE_PART>
__global__ __launch_bounds__(512)
void k_main(const int* __restrict__ itype, const int* __restrict__ nbr,
            const float* __restrict__ imdR, const float* __restrict__ nemb,
            const float* __restrict__ b1, const float* __restrict__ b2,
            const float* __restrict__ b3, const float* __restrict__ W4,
            const float* __restrict__ b4,
            float* __restrict__ ws, float* __restrict__ out)
{
    int base = blockIdx.x * ABLK;      // first atom (all 4 in same batch)
    int b    = base >> 8;
    int tid  = threadIdx.x;

    __shared__ float r_s[400], cut_s[400], sin_s[400];
    __shared__ float x_s[400], y_s[400], z_s[400];
    __shared__ int   nb_s[400];
    __shared__ float jjt_s[2000];        // [a*100+m][5]
    __shared__ float H_s[500];           // H fwd, dH bwd (reused)
    __shared__ float x1_s[400], t1_s[400], x3_s[400], t3_s[400], t5_s[400];
    __shared__ float g5_s[400], g3_s[400], g1_s[400];
    __shared__ float fbuf[NATOM * 3];    // per-batch force accumulator
    __shared__ int   t_s[4];

    // ---- phase 0: load geometry + types; zero fbuf ----
    if (tid < 4) t_s[tid] = itype[base + tid];
    for (int q = tid; q < NATOM * 3; q += 512) fbuf[q] = 0.f;
    if (tid < 400) {
        int a = tid / 100, m = tid - (tid / 100) * 100;
        int atom = base + a;
        float4 v = *reinterpret_cast<const float4*>(imdR + ((size_t)atom * MNBR + m) * 4);
        float r = v.x;
        r_s[tid] = r;
        float sc, cc; sincosf(PI_F * r, &sc, &cc);
        bool cond = (r < 6.0f && r > 0.0f);
        cut_s[tid] = cond ? (0.5f * cc + 0.5f) : 0.f;
        sin_s[tid] = cond ? sc : 0.f;
        x_s[tid] = v.y; y_s[tid] = v.z; z_s[tid] = v.w;
        int j = nbr[atom * MNBR + m];
        nb_s[tid] = j;
        int tj = (j > 0) ? itype[b * NATOM + (j - 1)] : 0;
        #pragma unroll
        for (int q = 0; q < 5; q++) jjt_s[tid * 5 + q] = nemb[tj * 5 + q];
    }
    __syncthreads();

    // ---- phase 1: H[a][q] = sum_m exp(-(r-rs_k)^2)*cut[m] * jjt[m][j] ----
    if (tid < 500) {
        int a = tid / 125, q = tid - (tid / 125) * 125;
        int k = q / 5, j = q - (q / 5) * 5;
        float rs = 0.5f + k * STEP;
        int am0 = a * 100;
        float acc = 0.f;
        for (int m = 0; m < MNBR; m++) {
            float r = r_s[am0 + m];
            float d = r - rs;
            float g = expf(-d * d);
            acc = fmaf(g * cut_s[am0 + m], jjt_s[(am0 + m) * 5 + j], acc);
        }
        H_s[tid] = acc;
    }
    __syncthreads();

    // ---- phase 2: x1 = H @ W1t[t].T + b1 ----
    if (tid < 400) {
        int a = tid / 100, jo = tid - (tid / 100) * 100;
        const float* wt = ws + OFF_W1TT + t_s[a] * 12500;   // [125][100]
        const float* hh = H_s + a * 125;
        float acc = 0.f;
        for (int q = 0; q < 125; q++) acc = fmaf(wt[q * 100 + jo], hh[q], acc);
        float v = acc + b1[jo];
        x1_s[tid] = v; t1_s[tid] = tanhf(v);
    }
    __syncthreads();

    // ---- phase 3: x3 = t1 @ W2.T + b2 + x1 ----
    if (tid < 400) {
        int a = tid / 100, jo = tid - (tid / 100) * 100;
        const float* wt = ws + OFF_W2T;
        const float* tt = t1_s + a * 100;
        float acc = 0.f;
        for (int k = 0; k < 100; k++) acc = fmaf(wt[k * 100 + jo], tt[k], acc);
        float v = acc + b2[jo] + x1_s[tid];
        x3_s[tid] = v; t3_s[tid] = tanhf(v);
    }
    __syncthreads();

    // ---- phase 4: x5 = t3 @ W3.T + b3 + x3 -> t5 ----
    if (tid < 400) {
        int a = tid / 100, jo = tid - (tid / 100) * 100;
        const float* wt = ws + OFF_W3T;
        const float* tt = t3_s + a * 100;
        float acc = 0.f;
        for (int k = 0; k < 100; k++) acc = fmaf(wt[k * 100 + jo], tt[k], acc);
        float v = acc + b3[jo] + x3_s[tid];
        t5_s[tid] = tanhf(v);
    }
    __syncthreads();

    // ---- phase 5a: Ei = t5.W4 + b4 (1 wave/atom) ; 5b: g5 = W4*(1-t5^2) ----
    if (tid < 256) {
        int a = tid >> 6, lane = tid & 63;
        float acc = 0.f;
        for (int j = lane; j < 100; j += 64) acc += t5_s[a * 100 + j] * W4[j];
        #pragma unroll
        for (int mm = 32; mm > 0; mm >>= 1) acc += __shfl_xor(acc, mm, 64);
        if (lane == 0) out[8 + base + a] = acc + b4[0];
    }
    if (tid < 400) {
        int jo = tid - (tid / 100) * 100;
        float t = t5_s[tid];
        g5_s[tid] = W4[jo] * (1.f - t * t);
    }
    __syncthreads();

    // ---- phase 6: g3 = g5 + (1-t3^2)*(g5 @ W3) ; W3T reused column-wise ----
    if (tid < 400) {
        int a = tid / 100, k = tid - (tid / 100) * 100;
        const float* gg = g5_s + a * 100;
        const float* wt = ws + OFF_W3T + k * 100;   // row k of W3T = col k of W3
        float acc = 0.f;
        for (int j = 0; j < 100; j++) acc = fmaf(wt[j], gg[j], acc);
        float t = t3_s[tid];
        g3_s[tid] = g5_s[tid] + (1.f - t * t) * acc;
    }
    __syncthreads();

    // ---- phase 7: g1 = g3 + (1-t1^2)*(g3 @ W2) ----
    if (tid < 400) {
        int a = tid / 100, k = tid - (tid / 100) * 100;
        const float* gg = g3_s + a * 100;
        const float* wt = ws + OFF_W2T + k * 100;
        float acc = 0.f;
        for (int j = 0; j < 100; j++) acc = fmaf(wt[j], gg[j], acc);
        float t = t1_s[tid];
        g1_s[tid] = g3_s[tid] + (1.f - t * t) * acc;
    }
    __syncthreads();

    // ---- phase 8: dH[q] = sum_jo g1[jo]*W1t[t][jo][q]  (overwrites H_s) ----
    if (tid < 500) {
        int a = tid / 125, q = tid - (tid / 125) * 125;
        const float* wt = ws + OFF_W1T + t_s[a] * 12500;    // [100][125]
        const float* gg = g1_s + a * 100;
        float acc = 0.f;
        for (int jo = 0; jo < 100; jo++) acc = fmaf(wt[jo * 125 + q], gg[jo], acc);
        H_s[tid] = acc;
    }
    __syncthreads();

    // ---- phase 9: force. wave w -> atom w>>1, half w&1 (lanes 0..49) ----
    {
        int w = tid >> 6, lane = tid & 63;
        int a = w >> 1, h = w & 1;
        float d0 = 0.f, d1 = 0.f, d2 = 0.f;
        if (lane < 50) {
            int am = a * 100 + h * 50 + lane;
            float r = r_s[am], cut = cut_s[am];
            float sterm = 0.5f * PI_F * sin_s[am];
            float j0 = jjt_s[am*5+0], j1v = jjt_s[am*5+1], j2 = jjt_s[am*5+2],
                  j3 = jjt_s[am*5+3], j4 = jjt_s[am*5+4];
            const float* dh0 = H_s + a * 125;
            float s = 0.f;
            for (int k = 0; k < NB; k++) {
                const float* dh = dh0 + k * 5;            // broadcast reads
                float dE = j0*dh[0] + j1v*dh[1] + j2*dh[2] + j3*dh[3] + j4*dh[4];
                float d  = r - (0.5f + k * STEP);
                float g  = expf(-d * d);
                float dfc = g * (-2.f * d) * cut - g * sterm;  // 0 when !cond
                s = fmaf(dE, dfc, s);
            }
            float inv = (r != 0.f) ? 1.f / r : 0.f;
            d0 = s * x_s[am] * inv; d1 = s * y_s[am] * inv; d2 = s * z_s[am] * inv;
            int j = nb_s[am];
            if (j > 0) {
                atomicAdd(&fbuf[(j - 1) * 3 + 0], d0);
                atomicAdd(&fbuf[(j - 1) * 3 + 1], d1);
                atomicAdd(&fbuf[(j - 1) * 3 + 2], d2);
            }
        }
        // self force: full-wave reduce (lanes >=50 contribute 0)
        #pragma unroll
        for (int mm = 32; mm > 0; mm >>= 1) {
            d0 += __shfl_xor(d0, mm, 64);
            d1 += __shfl_xor(d1, mm, 64);
            d2 += __shfl_xor(d2, mm, 64);
        }
        if (lane == 0) {
            int tl = (base + a) & 255;
            atomicAdd(&fbuf[tl * 3 + 0], -d0);
            atomicAdd(&fbuf[tl * 3 + 1], -d1);
            atomicAdd(&fbuf[tl * 3 + 2], -d2);
        }
    }
    __syncthreads();

    // ---- phase 10: export per-block force partial ----
    if (USE_PART) {
        for (int q = tid; q < NATOM * 3; q += 512)
            ws[OFF_PART + (size_t)blockIdx.x * 768 + q] = fbuf[q];
    } else {
        for (int q = tid; q < NATOM * 3; q += 512) {
            float vq = fbuf[q];
            if (vq != 0.f) atomicAdd(&out[8 + NATOT + (b << 8) * 3 + q], vq);
        }
    }
}

// ---------------------------------------------------------------------------
// K2: reduce force partials (64 per batch) + Etot from Ei. No atomics.
// ---------------------------------------------------------------------------
__global__ __launch_bounds__(256)
void k_red(const float* __restrict__ ws, float* __restrict__ out, int nfblk)
{
    int bid = blockIdx.x, tid = threadIdx.x;
    if (bid < nfblk) {
        int idx = bid * 256 + tid;              // 0..6143
        int b = idx / 768, q = idx - b * 768;
        float s = 0.f;
        #pragma unroll 8
        for (int p = 0; p < PPB; p++)
            s += ws[OFF_PART + (size_t)(b * PPB + p) * 768 + q];
        out[8 + NATOT + idx] = s;
    } else {
        int e = bid - nfblk;
        float v = out[8 + e * 256 + tid];       // Ei written by k_main
        #pragma unroll
        for (int mm = 32; mm > 0; mm >>= 1) v += __shfl_xor(v, mm, 64);
        __shared__ float wsum[4];
        if ((tid & 63) == 0) wsum[tid >> 6] = v;
        __syncthreads();
        if (tid == 0) out[e] = wsum[0] + wsum[1] + wsum[2] + wsum[3];
    }
}

// ---------------------------------------------------------------------------
extern "C" void kernel_launch(void* const* d_in, const int* in_sizes, int n_in,
                              void* d_out, int out_size, void* d_ws, size_t ws_size,
                              hipStream_t stream)
{
    (void)in_sizes; (void)n_in;

    const int*   itype = (const int*)  d_in[0];
    const int*   nbr   = (const int*)  d_in[1];
    const float* imdR  = (const float*)d_in[2];
    const float* nemb  = (const float*)d_in[3];
    const float* W1    = (const float*)d_in[4];
    const float* b1    = (const float*)d_in[5];
    const float* W2    = (const float*)d_in[6];
    const float* b2    = (const float*)d_in[7];
    const float* W3    = (const float*)d_in[8];
    const float* b3    = (const float*)d_in[9];
    const float* W4    = (const float*)d_in[10];
    const float* b4    = (const float*)d_in[11];

    float* out = (float*)d_out;
    float* ws  = (float*)d_ws;

    bool use_part = ws_size >= WS_NEED;     // ~2.15 MB; proven available
    if (!use_part)
        hipMemsetAsync((char*)d_out + (size_t)(8 + NATOT) * 4, 0,
                       (size_t)NATOT * 3 * 4, stream);

    hipLaunchKernelGGL(k_prep, dim3(600), dim3(128), 0, stream,
                       nemb, W1, W2, W3, ws);
    if (use_part) {
        hipLaunchKernelGGL((k_main<true>), dim3(NMBLK), dim3(512), 0, stream,
                           itype, nbr, imdR, nemb, b1, b2, b3, W4, b4, ws, out);
        hipLaunchKernelGGL(k_red, dim3(32), dim3(256), 0, stream, ws, out, 24);
    } else {
        hipLaunchKernelGGL((k_main<false>), dim3(NMBLK), dim3(512), 0, stream,
                           itype, nbr, imdR, nemb, b1, b2, b3, W4, b4, ws, out);
        hipLaunchKernelGGL(k_red, dim3(8), dim3(256), 0, stream, ws, out, 0);
    }
}

// Round 13
// 122.478 us; speedup vs baseline: 1.1146x; 1.1146x over previous
//
#include <hip/hip_runtime.h>
#include <math.h>

#define PI_F 3.14159274f        /* fp32 rounding of 3.141592653589 (== pi in fp32) */
#define STEP (5.5f/24.0f)       /* linspace(0.5, 6.0, 25) step */

constexpr int BATCH = 8;
constexpr int NATOM = 256;
constexpr int MNBR  = 100;
constexpr int NB    = 25;
constexpr int NATOT = BATCH * NATOM;   // 2048
constexpr int ABLK  = 4;               // atoms per main block
constexpr int NMBLK = NATOT / ABLK;    // 512 main blocks
constexpr int PPB   = NMBLK / BATCH;   // 64 force partials per batch

// ws layout (float offsets). W1 folded per center-type t (Imagetype in {1..4},
// plus padded type 0): W1t[t][jo][q] = sum_i W1[jo][k*25+i*5+j]*nemb[t][i],
// q = k*5+j (125-wide). H (125-wide) never leaves LDS in the fused kernel.
constexpr int OFF_W1T  = 0;            // [5][100][125]
constexpr int OFF_W1TT = 62500;        // [5][125][100] transposed
constexpr int OFF_W2T  = 125000;       // [100][100]
constexpr int OFF_W3T  = 135000;       // [100][100]
constexpr int OFF_PART = 145000;       // [512][768] force partials
constexpr size_t WS_NEED = (size_t)(OFF_PART + NMBLK * 768) * 4;   // ~2.15 MB

// ---------------------------------------------------------------------------
// K0: weight prep. Blocks 0..499: (t,jo) -> W1t / W1tT. Blocks 500..599:
//     transpose W2/W3.
// ---------------------------------------------------------------------------
__global__ __launch_bounds__(128)
void k_prep(const float* __restrict__ nemb, const float* __restrict__ W1,
            const float* __restrict__ W2, const float* __restrict__ W3,
            float* __restrict__ ws)
{
    int bid = blockIdx.x, tid = threadIdx.x;
    if (bid < 500) {
        int t = bid / 100, jo = bid - (bid / 100) * 100;
        if (tid < 125) {
            int k = tid / 5, j = tid - (tid / 5) * 5;
            float s = 0.f;
            #pragma unroll
            for (int i = 0; i < 5; i++)
                s = fmaf(W1[jo * 625 + k * 25 + i * 5 + j], nemb[t * 5 + i], s);
            ws[OFF_W1T  + (t * 100 + jo) * 125 + tid] = s;
            ws[OFF_W1TT + t * 12500 + tid * 100 + jo] = s;
        }
    } else {
        int jo = bid - 500;
        if (tid < 100) {
            ws[OFF_W2T + tid * 100 + jo] = W2[jo * 100 + tid];
            ws[OFF_W3T + tid * 100 + jo] = W3[jo * 100 + tid];
        }
    }
}

// ---------------------------------------------------------------------------
// K1: FUSED per-atom pipeline, 4 atoms/block (512 blocks x 512 thr, ~40 KB LDS).
//     Phase 1 restructured: thread=(m-quarter, atom, k) -> 25 iters, 1 exp +
//     5 j-fmas per iter (5x fewer exps, ~3.6x fewer phase-1 instructions).
//     Dot-product phases use 4-5 independent accumulators (chain-broken).
//     g5/g3/g1 alias the phase-1 partial buffer (disjoint lifetimes).
// ---------------------------------------------------------------------------
template<bool USE_PART>
__global__ __launch_bounds__(512)
void k_main(const int* __restrict__ itype, const int* __restrict__ nbr,
            const float* __restrict__ imdR, const float* __restrict__ nemb,
            const float* __restrict__ b1, const float* __restrict__ b2,
            const float* __restrict__ b3, const float* __restrict__ W4,
            const float* __restrict__ b4,
            float* __restrict__ ws, float* __restrict__ out)
{
    int base = blockIdx.x * ABLK;      // first atom (all 4 in same batch)
    int b    = base >> 8;
    int tid  = threadIdx.x;

    __shared__ float r_s[400], cut_s[400], sin_s[400];
    __shared__ float x_s[400], y_s[400], z_s[400];
    __shared__ int   nb_s[400];
    __shared__ float jjt_s[2000];        // [a*100+m][5]
    __shared__ float H_s[500];           // H fwd, dH bwd (reused)
    __shared__ float x1_s[400], t1_s[400], x3_s[400], t3_s[400], t5_s[400];
    __shared__ float scratch[2000];      // phase1 partials; later g5/g3/g1
    __shared__ float fbuf[NATOM * 3];    // per-batch force accumulator
    __shared__ int   t_s[4];

    float* g5_s = scratch;               // [400]
    float* g3_s = scratch + 500;         // [400]
    float* g1_s = scratch + 1000;        // [400]

    // ---- phase 0: load geometry + types; zero fbuf ----
    if (tid < 4) t_s[tid] = itype[base + tid];
    for (int q = tid; q < NATOM * 3; q += 512) fbuf[q] = 0.f;
    if (tid < 400) {
        int a = tid / 100, m = tid - (tid / 100) * 100;
        int atom = base + a;
        float4 v = *reinterpret_cast<const float4*>(imdR + ((size_t)atom * MNBR + m) * 4);
        float r = v.x;
        r_s[tid] = r;
        float sc, cc; sincosf(PI_F * r, &sc, &cc);
        bool cond = (r < 6.0f && r > 0.0f);
        cut_s[tid] = cond ? (0.5f * cc + 0.5f) : 0.f;
        sin_s[tid] = cond ? sc : 0.f;
        x_s[tid] = v.y; y_s[tid] = v.z; z_s[tid] = v.w;
        int j = nbr[atom * MNBR + m];
        nb_s[tid] = j;
        int tj = (j > 0) ? itype[b * NATOM + (j - 1)] : 0;
        #pragma unroll
        for (int q = 0; q < 5; q++) jjt_s[tid * 5 + q] = nemb[tj * 5 + q];
    }
    __syncthreads();

    // ---- phase 1a: partial H. thread=(c,a,k): m = c*25..c*25+24 ----
    //      1 exp per (m,k), shared across the 5 j's.
    if (tid < 400) {
        int c = tid / 100, rem = tid - (tid / 100) * 100;
        int a = rem / 25, k = rem - (rem / 25) * 25;
        float rs = 0.5f + k * STEP;
        int am0 = a * 100 + c * 25;
        float ac0 = 0.f, ac1 = 0.f, ac2 = 0.f, ac3 = 0.f, ac4 = 0.f;
        for (int m = 0; m < 25; m++) {
            int am = am0 + m;
            float d = r_s[am] - rs;
            float g = __expf(-d * d) * cut_s[am];
            const float* jj = jjt_s + am * 5;
            ac0 = fmaf(g, jj[0], ac0);
            ac1 = fmaf(g, jj[1], ac1);
            ac2 = fmaf(g, jj[2], ac2);
            ac3 = fmaf(g, jj[3], ac3);
            ac4 = fmaf(g, jj[4], ac4);
        }
        // index (c*100 + a*25 + k)*5 + j  ==  c*500 + (a*125 + k*5 + j)
        float* pp = scratch + tid * 5;
        pp[0] = ac0; pp[1] = ac1; pp[2] = ac2; pp[3] = ac3; pp[4] = ac4;
    }
    __syncthreads();

    // ---- phase 1b: reduce 4 m-quarters -> H_s[a*125+q] ----
    if (tid < 500)
        H_s[tid] = (scratch[tid] + scratch[500 + tid])
                 + (scratch[1000 + tid] + scratch[1500 + tid]);
    __syncthreads();

    // ---- phase 2: x1 = H @ W1t[t].T + b1 (5-way accum, coalesced W1tT) ----
    if (tid < 400) {
        int a = tid / 100, jo = tid - (tid / 100) * 100;
        const float* wt = ws + OFF_W1TT + t_s[a] * 12500 + jo;  // [125][100]
        const float* hh = H_s + a * 125;
        float a0 = 0.f, a1 = 0.f, a2 = 0.f, a3 = 0.f, a4 = 0.f;
        for (int q = 0; q < 125; q += 5) {
            a0 = fmaf(wt[(q + 0) * 100], hh[q + 0], a0);
            a1 = fmaf(wt[(q + 1) * 100], hh[q + 1], a1);
            a2 = fmaf(wt[(q + 2) * 100], hh[q + 2], a2);
            a3 = fmaf(wt[(q + 3) * 100], hh[q + 3], a3);
            a4 = fmaf(wt[(q + 4) * 100], hh[q + 4], a4);
        }
        float v = ((a0 + a1) + (a2 + a3)) + a4 + b1[jo];
        x1_s[tid] = v; t1_s[tid] = tanhf(v);
    }
    __syncthreads();

    // ---- phase 3: x3 = t1 @ W2.T + b2 + x1 (4-way accum) ----
    if (tid < 400) {
        int a = tid / 100, jo = tid - (tid / 100) * 100;
        const float* wt = ws + OFF_W2T + jo;
        const float* tt = t1_s + a * 100;
        float a0 = 0.f, a1 = 0.f, a2 = 0.f, a3 = 0.f;
        for (int k = 0; k < 100; k += 4) {
            a0 = fmaf(wt[(k + 0) * 100], tt[k + 0], a0);
            a1 = fmaf(wt[(k + 1) * 100], tt[k + 1], a1);
            a2 = fmaf(wt[(k + 2) * 100], tt[k + 2], a2);
            a3 = fmaf(wt[(k + 3) * 100], tt[k + 3], a3);
        }
        float v = (a0 + a1) + (a2 + a3) + b2[jo] + x1_s[tid];
        x3_s[tid] = v; t3_s[tid] = tanhf(v);
    }
    __syncthreads();

    // ---- phase 4: x5 = t3 @ W3.T + b3 + x3 -> t5 ----
    if (tid < 400) {
        int a = tid / 100, jo = tid - (tid / 100) * 100;
        const float* wt = ws + OFF_W3T + jo;
        const float* tt = t3_s + a * 100;
        float a0 = 0.f, a1 = 0.f, a2 = 0.f, a3 = 0.f;
        for (int k = 0; k < 100; k += 4) {
            a0 = fmaf(wt[(k + 0) * 100], tt[k + 0], a0);
            a1 = fmaf(wt[(k + 1) * 100], tt[k + 1], a1);
            a2 = fmaf(wt[(k + 2) * 100], tt[k + 2], a2);
            a3 = fmaf(wt[(k + 3) * 100], tt[k + 3], a3);
        }
        float v = (a0 + a1) + (a2 + a3) + b3[jo] + x3_s[tid];
        t5_s[tid] = tanhf(v);
    }
    __syncthreads();

    // ---- phase 5a: Ei (1 wave/atom) ; 5b: g5 = W4*(1-t5^2) ----
    if (tid < 256) {
        int a = tid >> 6, lane = tid & 63;
        float acc = 0.f;
        for (int j = lane; j < 100; j += 64) acc += t5_s[a * 100 + j] * W4[j];
        #pragma unroll
        for (int mm = 32; mm > 0; mm >>= 1) acc += __shfl_xor(acc, mm, 64);
        if (lane == 0) out[8 + base + a] = acc + b4[0];
    }
    if (tid < 400) {
        int jo = tid - (tid / 100) * 100;
        float t = t5_s[tid];
        g5_s[tid] = W4[jo] * (1.f - t * t);
    }
    __syncthreads();

    // ---- phase 6: g3 = g5 + (1-t3^2)*(g5 @ W3) ----
    if (tid < 400) {
        int a = tid / 100, k = tid - (tid / 100) * 100;
        const float* gg = g5_s + a * 100;
        const float* wt = ws + OFF_W3T + k * 100;   // row k of W3T = col k of W3
        float a0 = 0.f, a1 = 0.f, a2 = 0.f, a3 = 0.f;
        for (int j = 0; j < 100; j += 4) {
            a0 = fmaf(wt[j + 0], gg[j + 0], a0);
            a1 = fmaf(wt[j + 1], gg[j + 1], a1);
            a2 = fmaf(wt[j + 2], gg[j + 2], a2);
            a3 = fmaf(wt[j + 3], gg[j + 3], a3);
        }
        float t = t3_s[tid];
        g3_s[tid] = g5_s[tid] + (1.f - t * t) * ((a0 + a1) + (a2 + a3));
    }
    __syncthreads();

    // ---- phase 7: g1 = g3 + (1-t1^2)*(g3 @ W2) ----
    if (tid < 400) {
        int a = tid / 100, k = tid - (tid / 100) * 100;
        const float* gg = g3_s + a * 100;
        const float* wt = ws + OFF_W2T + k * 100;
        float a0 = 0.f, a1 = 0.f, a2 = 0.f, a3 = 0.f;
        for (int j = 0; j < 100; j += 4) {
            a0 = fmaf(wt[j + 0], gg[j + 0], a0);
            a1 = fmaf(wt[j + 1], gg[j + 1], a1);
            a2 = fmaf(wt[j + 2], gg[j + 2], a2);
            a3 = fmaf(wt[j + 3], gg[j + 3], a3);
        }
        float t = t1_s[tid];
        g1_s[tid] = g3_s[tid] + (1.f - t * t) * ((a0 + a1) + (a2 + a3));
    }
    __syncthreads();

    // ---- phase 8: dH[q] = sum_jo g1[jo]*W1t[t][jo][q] (overwrites H_s) ----
    if (tid < 500) {
        int a = tid / 125, q = tid - (tid / 125) * 125;
        const float* wt = ws + OFF_W1T + t_s[a] * 12500 + q;    // [100][125]
        const float* gg = g1_s + a * 100;
        float a0 = 0.f, a1 = 0.f, a2 = 0.f, a3 = 0.f;
        for (int jo = 0; jo < 100; jo += 4) {
            a0 = fmaf(wt[(jo + 0) * 125], gg[jo + 0], a0);
            a1 = fmaf(wt[(jo + 1) * 125], gg[jo + 1], a1);
            a2 = fmaf(wt[(jo + 2) * 125], gg[jo + 2], a2);
            a3 = fmaf(wt[(jo + 3) * 125], gg[jo + 3], a3);
        }
        H_s[tid] = (a0 + a1) + (a2 + a3);
    }
    __syncthreads();

    // ---- phase 9: force. wave w -> atom w>>1, half w&1 (lanes 0..49) ----
    {
        int w = tid >> 6, lane = tid & 63;
        int a = w >> 1, h = w & 1;
        float d0 = 0.f, d1 = 0.f, d2 = 0.f;
        if (lane < 50) {
            int am = a * 100 + h * 50 + lane;
            float r = r_s[am], cut = cut_s[am];
            float sterm = 0.5f * PI_F * sin_s[am];
            float j0 = jjt_s[am*5+0], j1v = jjt_s[am*5+1], j2 = jjt_s[am*5+2],
                  j3 = jjt_s[am*5+3], j4 = jjt_s[am*5+4];
            const float* dh0 = H_s + a * 125;
            float s = 0.f;
            for (int k = 0; k < NB; k++) {
                const float* dh = dh0 + k * 5;            // broadcast reads
                float dE = j0*dh[0] + j1v*dh[1] + j2*dh[2] + j3*dh[3] + j4*dh[4];
                float d  = r - (0.5f + k * STEP);
                float g  = __expf(-d * d);
                float dfc = g * (-2.f * d) * cut - g * sterm;  // 0 when !cond
                s = fmaf(dE, dfc, s);
            }
            float inv = (r != 0.f) ? 1.f / r : 0.f;
            d0 = s * x_s[am] * inv; d1 = s * y_s[am] * inv; d2 = s * z_s[am] * inv;
            int j = nb_s[am];
            if (j > 0) {
                atomicAdd(&fbuf[(j - 1) * 3 + 0], d0);
                atomicAdd(&fbuf[(j - 1) * 3 + 1], d1);
                atomicAdd(&fbuf[(j - 1) * 3 + 2], d2);
            }
        }
        // self force: full-wave reduce (lanes >=50 contribute 0)
        #pragma unroll
        for (int mm = 32; mm > 0; mm >>= 1) {
            d0 += __shfl_xor(d0, mm, 64);
            d1 += __shfl_xor(d1, mm, 64);
            d2 += __shfl_xor(d2, mm, 64);
        }
        if (lane == 0) {
            int tl = (base + a) & 255;
            atomicAdd(&fbuf[tl * 3 + 0], -d0);
            atomicAdd(&fbuf[tl * 3 + 1], -d1);
            atomicAdd(&fbuf[tl * 3 + 2], -d2);
        }
    }
    __syncthreads();

    // ---- phase 10: export per-block force partial ----
    if (USE_PART) {
        for (int q = tid; q < NATOM * 3; q += 512)
            ws[OFF_PART + (size_t)blockIdx.x * 768 + q] = fbuf[q];
    } else {
        for (int q = tid; q < NATOM * 3; q += 512) {
            float vq = fbuf[q];
            if (vq != 0.f) atomicAdd(&out[8 + NATOT + (b << 8) * 3 + q], vq);
        }
    }
}

// ---------------------------------------------------------------------------
// K2: reduce force partials (64 per batch) + Etot from Ei. No atomics.
// ---------------------------------------------------------------------------
__global__ __launch_bounds__(256)
void k_red(const float* __restrict__ ws, float* __restrict__ out, int nfblk)
{
    int bid = blockIdx.x, tid = threadIdx.x;
    if (bid < nfblk) {
        int idx = bid * 256 + tid;              // 0..6143
        int b = idx / 768, q = idx - b * 768;
        float s = 0.f;
        #pragma unroll 8
        for (int p = 0; p < PPB; p++)
            s += ws[OFF_PART + (size_t)(b * PPB + p) * 768 + q];
        out[8 + NATOT + idx] = s;
    } else {
        int e = bid - nfblk;
        float v = out[8 + e * 256 + tid];       // Ei written by k_main
        #pragma unroll
        for (int mm = 32; mm > 0; mm >>= 1) v += __shfl_xor(v, mm, 64);
        __shared__ float wsum[4];
        if ((tid & 63) == 0) wsum[tid >> 6] = v;
        __syncthreads();
        if (tid == 0) out[e] = wsum[0] + wsum[1] + wsum[2] + wsum[3];
    }
}

// ---------------------------------------------------------------------------
extern "C" void kernel_launch(void* const* d_in, const int* in_sizes, int n_in,
                              void* d_out, int out_size, void* d_ws, size_t ws_size,
                              hipStream_t stream)
{
    (void)in_sizes; (void)n_in;

    const int*   itype = (const int*)  d_in[0];
    const int*   nbr   = (const int*)  d_in[1];
    const float* imdR  = (const float*)d_in[2];
    const float* nemb  = (const float*)d_in[3];
    const float* W1    = (const float*)d_in[4];
    const float* b1    = (const float*)d_in[5];
    const float* W2    = (const float*)d_in[6];
    const float* b2    = (const float*)d_in[7];
    const float* W3    = (const float*)d_in[8];
    const float* b3    = (const float*)d_in[9];
    const float* W4    = (const float*)d_in[10];
    const float* b4    = (const float*)d_in[11];

    float* out = (float*)d_out;
    float* ws  = (float*)d_ws;

    bool use_part = ws_size >= WS_NEED;     // ~2.15 MB; proven available
    if (!use_part)
        hipMemsetAsync((char*)d_out + (size_t)(8 + NATOT) * 4, 0,
                       (size_t)NATOT * 3 * 4, stream);

    hipLaunchKernelGGL(k_prep, dim3(600), dim3(128), 0, stream,
                       nemb, W1, W2, W3, ws);
    if (use_part) {
        hipLaunchKernelGGL((k_main<true>), dim3(NMBLK), dim3(512), 0, stream,
                           itype, nbr, imdR, nemb, b1, b2, b3, W4, b4, ws, out);
        hipLaunchKernelGGL(k_red, dim3(32), dim3(256), 0, stream, ws, out, 24);
    } else {
        hipLaunchKernelGGL((k_main<false>), dim3(NMBLK), dim3(512), 0, stream,
                           itype, nbr, imdR, nemb, b1, b2, b3, W4, b4, ws, out);
        hipLaunchKernelGGL(k_red, dim3(8), dim3(256), 0, stream, ws, out, 0);
    }
}